// Round 12
// baseline (399.789 us; speedup 1.0000x reference)
//
#include <hip/hip_runtime.h>

#define B_    64
#define C_    256
#define HW_   1024
#define NPIX  (B_ * HW_)
#define K_    1024
#define TAU_FLAG    2.0e-4f
#define CAND_MARGIN 2.2e-4f
#define MAXFLAG     8192
#define MAXCAND     65536

typedef unsigned short u16;
typedef unsigned int   u32;
typedef unsigned long long u64;
typedef __attribute__((ext_vector_type(8))) __bf16 bf16x8v;
typedef __attribute__((ext_vector_type(4))) float  float4v;
typedef __attribute__((address_space(1))) void gvoid;
typedef __attribute__((address_space(3))) void lvoid;

// Rounding barriers: force a separately-rounded f32 mul/add/sub (defeat
// -ffp-contract=fast fusion and any reassociation across the boundary).
__device__ __forceinline__ float fmul_x(float a, float b) { float p = a * b; asm volatile("" : "+v"(p)); return p; }
__device__ __forceinline__ float fadd_x(float a, float b) { float s = a + b; asm volatile("" : "+v"(s)); return s; }
__device__ __forceinline__ float fsub_x(float a, float b) { float s = a - b; asm volatile("" : "+v"(s)); return s; }

// f32 -> bf16 round-to-nearest-even (finite inputs only), and back.
__device__ __forceinline__ u16 bf16_rne(float f) {
    u32 u = __float_as_uint(f);
    u32 r = u + 0x7FFFu + ((u >> 16) & 1u);
    return (u16)(r >> 16);
}
__device__ __forceinline__ float bf16_to_f(u16 h) { return __uint_as_float(((u32)h) << 16); }

__device__ __forceinline__ uint4 pack8(const u16* h) {
    return make_uint4((u32)h[0] | ((u32)h[1] << 16), (u32)h[2] | ((u32)h[3] << 16),
                      (u32)h[4] | ((u32)h[5] << 16), (u32)h[6] | ((u32)h[7] << 16));
}

// ---------------------------------------------------------------------------
// numpy pairwise sum replica for 256 contiguous squares (unchanged).
// ---------------------------------------------------------------------------
__device__ __forceinline__ float np_sumsq_256(const float* __restrict__ a) {
    float half[2];
#pragma unroll
    for (int h = 0; h < 2; ++h) {
        const float* p = a + h * 128;
        float r[8];
#pragma unroll
        for (int j = 0; j < 8; ++j) r[j] = fmul_x(p[j], p[j]);
        for (int i = 8; i < 128; i += 8)
#pragma unroll
            for (int j = 0; j < 8; ++j) r[j] = fadd_x(r[j], fmul_x(p[i + j], p[i + j]));
        half[h] = fadd_x(fadd_x(fadd_x(r[0], r[1]), fadd_x(r[2], r[3])),
                         fadd_x(fadd_x(r[4], r[5]), fadd_x(r[6], r[7])));
    }
    return fadd_x(half[0], half[1]);
}

// ---------------------------------------------------------------------------
// numpy einsum f32 dot replica (unchanged).
// ---------------------------------------------------------------------------
__device__ float np_einsum_dot_256(const float* __restrict__ xr,
                                   const float* __restrict__ er) {
    float acc0 = 0.f, acc1 = 0.f, acc2 = 0.f, acc3 = 0.f;
    for (int blk = 0; blk < 256; blk += 16) {
#pragma unroll
        for (int sub = 3; sub >= 0; --sub) {
            const int base = blk + sub * 4;
            acc0 = fadd_x(acc0, fmul_x(xr[base + 0], er[base + 0]));
            acc1 = fadd_x(acc1, fmul_x(xr[base + 1], er[base + 1]));
            acc2 = fadd_x(acc2, fmul_x(xr[base + 2], er[base + 2]));
            acc3 = fadd_x(acc3, fmul_x(xr[base + 3], er[base + 3]));
        }
    }
    return fadd_x(fadd_x(acc0, acc2), fadd_x(acc1, acc3));
}

// ---------------------------------------------------------------------------
__global__ __launch_bounds__(256) void zero_kernel(int* pcount, int* ccount) {
    if (threadIdx.x == 0 && blockIdx.x == 0) { *pcount = 0; *ccount = 0; }
}

// e_sq via numpy-pairwise replica (unchanged).
__global__ __launch_bounds__(256) void esq_np_kernel(const float* __restrict__ emb,
                                                     float* __restrict__ esq) {
    const int k = blockIdx.x * 256 + threadIdx.x;
    esq[k] = np_sumsq_256(emb + (size_t)k * C_);
}

// ---------------------------------------------------------------------------
// emb f32 -> hi/lo bf16 planes in STAGED-TILE layout (unchanged):
// chunk (kb*4+ct) is 16KB/plane: [cg8][128][8].
// ---------------------------------------------------------------------------
__global__ __launch_bounds__(256) void cvt_e_kernel(const float* __restrict__ emb,
                                                    u16* __restrict__ et_hi,
                                                    u16* __restrict__ et_lo) {
    const int tid = threadIdx.x;
    const int k  = (blockIdx.x << 5) + (tid & 31);
    const int cg = tid >> 5;
    const int kb = k >> 7;
    const int kr = k & 127;
#pragma unroll
    for (int ct = 0; ct < 4; ++ct) {
        const int c = (ct << 6) + (cg << 3);
        const float* src = emb + (size_t)k * C_ + c;
        u16 h[8], l[8];
#pragma unroll
        for (int i = 0; i < 8; ++i) {
            const float f = src[i];
            h[i] = bf16_rne(f);
            l[i] = bf16_rne(f - bf16_to_f(h[i]));
        }
        const size_t off = ((size_t)((kb << 2) + ct) << 13) + (cg << 10) + (kr << 3);
        *(uint4*)(et_hi + off) = pack8(h);
        *(uint4*)(et_lo + off) = pack8(l);
    }
}

// ---------------------------------------------------------------------------
// x f32 -> hi/lo bf16 planes in 64-ROW chunk layout (unchanged):
// chunk (pb*4+ct) is 8KB/plane: [cg8][row64][8].
// ---------------------------------------------------------------------------
__global__ __launch_bounds__(256) void cvt_x_kernel(const float* __restrict__ x,
                                                    u16* __restrict__ xt_hi,
                                                    u16* __restrict__ xt_lo) {
    __shared__ float xs[256][36];       // [c][px(32)+pad]
    const int tid = threadIdx.x;
    const int pix0 = blockIdx.x << 5;   // 32 pixels per block
    const int b   = pix0 >> 10;
    const int hw0 = pix0 & 1023;
#pragma unroll
    for (int r8 = 0; r8 < 8; ++r8) {
        const int u = (r8 << 8) + tid;  // 0..2047 float4s
        const int c = u >> 3;
        const int hq = (u & 7) << 2;
        const float4 v = *(const float4*)(x + ((size_t)b * C_ + c) * HW_ + hw0 + hq);
        *(float4*)&xs[c][hq] = v;
    }
    __syncthreads();
    const int cg = tid >> 5;            // 0..7
    const int px = tid & 31;            // 0..31
    const int pb = pix0 >> 6;           // 64-px chunk index
    const int r  = (pix0 & 63) + px;    // row within chunk
#pragma unroll
    for (int ct = 0; ct < 4; ++ct) {
        const int c = (ct << 6) + (cg << 3);
        u16 h[8], l[8];
#pragma unroll
        for (int i = 0; i < 8; ++i) {
            const float f = xs[c + i][px];
            h[i] = bf16_rne(f);
            l[i] = bf16_rne(f - bf16_to_f(h[i]));
        }
        const size_t off = ((size_t)((pb << 2) + ct) << 12) + (cg << 9) + (r << 3);
        *(uint4*)(xt_hi + off) = pack8(h);
        *(uint4*)(xt_lo + off) = pack8(l);
    }
}

// ---------------------------------------------------------------------------
// MFMA bf16x3 scoring + top-2 + flag. v6: BIG WAVE TILE (64px x 64codes,
// pf=4 x cf=4 -> 48 MFMA per 16 ds_read_b128, ratio 3 vs r8's 1.5).
// Block = 64 px, 512 threads, 8 waves; wave w owns codes half*512 + w*64.
// K-loop = 2 halves x 8 kg steps = 16 steps (vs 64). X both planes (64KB)
// LDS-persistent; single 64KB E buffer staged per step ([plane2][kb4][cg4]
// [128][8] image of the et tiles), r8's proven 2-barrier schedule.
// LDS 128KB -> 1 block/CU, 8 waves (2/SIMD); total LDS reads halved
// (4.19M -> 2.1M b128). Scores bitwise identical to rounds 2-11: same
// 3-MFMA chain per (pixel,code) over the same kg-ascending channel groups,
// identical lane-slot maps for A and B, per-thread k ascending
// (half -> cf -> r), order-independent merge w/ explicit index tie-break.
// ---------------------------------------------------------------------------
__global__ __launch_bounds__(512, 2) void vq_main_mfma(const u16* __restrict__ xt_hi,
                                                       const u16* __restrict__ xt_lo,
                                                       const u16* __restrict__ et_hi,
                                                       const u16* __restrict__ et_lo,
                                                       const float* __restrict__ esq,
                                                       int* __restrict__ idx_arr,
                                                       float* __restrict__ m1_arr,
                                                       int* __restrict__ plist,
                                                       int* __restrict__ pcount) {
    // XH 32K @0 | XL 32K @32768 | E 64K @65536 ([pl2][kb4][cg4][128][8])
    __shared__ __align__(16) char smem[131072];
    float* r_m1 = (float*)(smem + 65536);   // aliases E after the k-loop
    float* r_m2 = (float*)(smem + 74240);   // 64*33*4 = 8448 each
    int*   r_i1 = (int*)(smem + 82944);

    const int tid  = threadIdx.x;
    const int lane = tid & 63;
    const int wid  = tid >> 6;        // 0..7: code-group owner
    const int l15 = lane & 15, l4 = lane >> 4;
    const int p0 = blockIdx.x * 64;

    const char* xhb = (const char*)xt_hi + ((size_t)blockIdx.x << 15); // 32KB/block
    const char* xlb = (const char*)xt_lo + ((size_t)blockIdx.x << 15);

    // ---- prologue: stage persistent X (linear copy, 8 loads/wave) ----
#pragma unroll
    for (int i = 0; i < 4; ++i) {
        const int seg = (i << 3) + wid;     // 0..31, wave-uniform
        __builtin_amdgcn_global_load_lds((gvoid*)(xhb + (seg << 10) + (lane << 4)),
            (lvoid*)(smem + (seg << 10)), 16, 0, 0);
        __builtin_amdgcn_global_load_lds((gvoid*)(xlb + (seg << 10) + (lane << 4)),
            (lvoid*)(smem + 32768 + (seg << 10)), 16, 0, 0);
    }

    float m1[4], m2[4]; int i1[4];
#pragma unroll
    for (int i = 0; i < 4; ++i) { m1[i] = 3.0e38f; m2[i] = 3.0e38f; i1[i] = 0; }

    for (int half = 0; half < 2; ++half) {
        float4v acc[4][4];
        const float4v zero4 = {0.f, 0.f, 0.f, 0.f};
#pragma unroll
        for (int pf = 0; pf < 4; ++pf)
#pragma unroll
            for (int cf = 0; cf < 4; ++cf) acc[pf][cf] = zero4;

#pragma unroll
        for (int kg = 0; kg < 8; ++kg) {
            __syncthreads();    // E buffer free (prev step consumed; X ok @first)
            {   // stage E 64KB: 512 codes x 32ch x 2 planes; 8 loads/wave.
                // seg s (0..31/plane): kb = s>>3, cg' = (s>>1)&3, codehalf = s&1
#pragma unroll
                for (int i = 0; i < 4; ++i) {
                    const int s = (wid << 2) + i;          // 0..31, wave-uniform
                    const size_t chunk = ((size_t)(((half << 2) + (s >> 3)) * 4 + (kg >> 1))) << 14;
                    const size_t goff = chunk + ((size_t)(kg & 1) << 13) +
                                        (size_t)(((s >> 1) & 3) << 11) + ((s & 1) << 10) + (lane << 4);
                    __builtin_amdgcn_global_load_lds((gvoid*)((const char*)et_hi + goff),
                        (lvoid*)(smem + 65536 + (s << 10)), 16, 0, 0);
                    __builtin_amdgcn_global_load_lds((gvoid*)((const char*)et_lo + goff),
                        (lvoid*)(smem + 65536 + 32768 + (s << 10)), 16, 0, 0);
                }
            }
            __syncthreads();    // E landed (syncthreads drains vmcnt)

            // E fragments: wave's 64 codes = kb_local (wid>>1), code_in_kb
            // (wid&1)*64 + cf*16 + l15, cg' = l4.
            bf16x8v eh[4], el[4];
#pragma unroll
            for (int cf = 0; cf < 4; ++cf) {
                const int eo = 65536 + ((wid >> 1) << 13) + (l4 << 11) +
                               ((((wid & 1) << 6) + (cf << 4) + l15) << 4);
                eh[cf] = *(const bf16x8v*)(smem + eo);
                el[cf] = *(const bf16x8v*)(smem + 32768 + eo);
            }
            const int ct = kg >> 1;
            const int cg = ((kg & 1) << 2) + l4;
#pragma unroll
            for (int pf = 0; pf < 4; ++pf) {
                const int xo = (ct << 13) + (cg << 10) + (((pf << 4) + l15) << 4);
                const bf16x8v xh = *(const bf16x8v*)(smem + xo);
                const bf16x8v xl = *(const bf16x8v*)(smem + 32768 + xo);
#pragma unroll
                for (int cf = 0; cf < 4; ++cf) {
                    acc[pf][cf] = __builtin_amdgcn_mfma_f32_16x16x32_bf16(eh[cf], xh, acc[pf][cf], 0, 0, 0);
                    acc[pf][cf] = __builtin_amdgcn_mfma_f32_16x16x32_bf16(eh[cf], xl, acc[pf][cf], 0, 0, 0);
                    acc[pf][cf] = __builtin_amdgcn_mfma_f32_16x16x32_bf16(el[cf], xh, acc[pf][cf], 0, 0, 0);
                }
            }
        }
        // top-2 update for this half's 64 codes; k ascending per pixel slot
        // (cf outer, reg inner, halves outer-most) — same fmaf score formula.
        const int k0 = (half << 9) + (wid << 6);
#pragma unroll
        for (int cf = 0; cf < 4; ++cf) {
            const int kb = k0 + (cf << 4) + (l4 << 2);
            const float4v ev = *(const float4v*)(esq + kb);
#pragma unroll
            for (int pf = 0; pf < 4; ++pf) {
#pragma unroll
                for (int r = 0; r < 4; ++r) {
                    const float s = fmaf(-2.0f, acc[pf][cf][r], ev[r]);
                    const int k = kb + r;
                    if (s < m1[pf])      { m2[pf] = m1[pf]; m1[pf] = s; i1[pf] = k; }
                    else if (s < m2[pf]) { m2[pf] = s; }
                }
            }
        }
    }

    __syncthreads();    // E dead; alias reduction arrays (32 slots/pixel)
#pragma unroll
    for (int pf = 0; pf < 4; ++pf) {
        const int p = (pf << 4) + l15;          // 0..63
        const int slot = (wid << 2) + l4;       // 0..31
        r_m1[p * 33 + slot] = m1[pf]; r_m2[p * 33 + slot] = m2[pf]; r_i1[p * 33 + slot] = i1[pf];
    }
    __syncthreads();
    if (tid < 64) {
        const int p = tid;
        float M1 = r_m1[p * 33 + 0], M2 = r_m2[p * 33 + 0];
        int   I1 = r_i1[p * 33 + 0];
        for (int t = 1; t < 32; ++t) {
            const float a1 = r_m1[p * 33 + t], a2 = r_m2[p * 33 + t];
            const int   ai = r_i1[p * 33 + t];
            if (a1 < M1 || (a1 == M1 && ai < I1)) { M2 = fminf(M1, a2); M1 = a1; I1 = ai; }
            else                                  { M2 = fminf(M2, a1); }
        }
        const int pix = p0 + p;
        idx_arr[pix] = I1;
        m1_arr[pix] = M1;
        if (M2 - M1 <= TAU_FLAG) {
            int pos = atomicAdd(pcount, 1);
            if (pos < MAXFLAG) plist[pos] = pix;
        }
    }
}

// ---------------------------------------------------------------------------
// gather_x: compact flagged-pixel columns into xg[slot][256]; numpy-pairwise
// sumsq via the 16-chain parallel tree; init best_arr. (unchanged)
// ---------------------------------------------------------------------------
__global__ __launch_bounds__(256) void gather_x_kernel(const float* __restrict__ x,
                                                       const int* __restrict__ plist,
                                                       const int* __restrict__ pcount,
                                                       float* __restrict__ xg,
                                                       float* __restrict__ xsq_arr,
                                                       u64* __restrict__ best_arr) {
    __shared__ float xs[256];
    __shared__ float rsum[16];
    const int nflag = min(*pcount, MAXFLAG);
    const int slot = blockIdx.x;
    if (slot >= nflag) return;
    const int tid = threadIdx.x;
    const int pix = plist[slot];
    const int b = pix >> 10, hw = pix & 1023;
    const float v = x[((size_t)(b * C_ + tid)) * HW_ + hw];
    xs[tid] = v;
    xg[(size_t)slot * C_ + tid] = v;
    __syncthreads();
    if (tid < 16) {
        const int h = tid >> 3, j = tid & 7;
        const float* q = &xs[h * 128];
        float r = fmul_x(q[j], q[j]);
        for (int i = 8; i < 128; i += 8) r = fadd_x(r, fmul_x(q[i + j], q[i + j]));
        rsum[h * 8 + j] = r;
    }
    __syncthreads();
    if (tid == 0) {
        const float h0 = fadd_x(fadd_x(fadd_x(rsum[0], rsum[1]), fadd_x(rsum[2], rsum[3])),
                                fadd_x(fadd_x(rsum[4], rsum[5]), fadd_x(rsum[6], rsum[7])));
        const float h1 = fadd_x(fadd_x(fadd_x(rsum[8], rsum[9]), fadd_x(rsum[10], rsum[11])),
                                fadd_x(fadd_x(rsum[12], rsum[13]), fadd_x(rsum[14], rsum[15])));
        xsq_arr[slot] = fadd_x(h0, h1);
        best_arr[slot] = ~0ull;
    }
}

// ---------------------------------------------------------------------------
// xg f32 (row-major, like emb) -> hi/lo bf16 staged tiles, 128-row chunks
// (scan kernel layout). (unchanged)
// ---------------------------------------------------------------------------
__global__ __launch_bounds__(256) void cvt_xg_kernel(const float* __restrict__ xg,
                                                     const int* __restrict__ pcount,
                                                     u16* __restrict__ xgt_hi,
                                                     u16* __restrict__ xgt_lo) {
    const int nflag = min(*pcount, MAXFLAG);
    if ((int)(blockIdx.x << 5) >= nflag) return;
    const int tid = threadIdx.x;
    const int s  = (blockIdx.x << 5) + (tid & 31);
    const int cg = tid >> 5;
    const int sb = s >> 7;
    const int sr = s & 127;
#pragma unroll
    for (int ct = 0; ct < 4; ++ct) {
        const int c = (ct << 6) + (cg << 3);
        const float* src = xg + (size_t)s * C_ + c;   // tail slots: garbage, guarded later
        u16 h[8], l[8];
#pragma unroll
        for (int i = 0; i < 8; ++i) {
            const float f = src[i];
            h[i] = bf16_rne(f);
            l[i] = bf16_rne(f - bf16_to_f(h[i]));
        }
        const size_t off = ((size_t)((sb << 2) + ct) << 13) + (cg << 10) + (sr << 3);
        *(uint4*)(xgt_hi + off) = pack8(h);
        *(uint4*)(xgt_lo + off) = pack8(l);
    }
}

// ---------------------------------------------------------------------------
// MFMA scan of flagged slots (unchanged): 128 slots x 128 codes per block;
// candidates appended to a global list.
// ---------------------------------------------------------------------------
__global__ __launch_bounds__(256) void vq_scan_mfma(const u16* __restrict__ xgt_hi,
                                                    const u16* __restrict__ xgt_lo,
                                                    const u16* __restrict__ et_hi,
                                                    const u16* __restrict__ et_lo,
                                                    const float* __restrict__ esq,
                                                    const float* __restrict__ m1_arr,
                                                    const int* __restrict__ plist,
                                                    const int* __restrict__ pcount,
                                                    u32* __restrict__ cand,
                                                    int* __restrict__ ccount) {
    __shared__ __align__(16) u16 xsb_hi[8192], xsb_lo[8192], esb_hi[8192], esb_lo[8192];
    __shared__ float thresh_s[128];

    const int nflag = min(*pcount, MAXFLAG);
    const int st = blockIdx.x >> 3;     // slot tile
    const int kt = blockIdx.x & 7;      // code tile
    const int p0 = st << 7;
    if (p0 >= nflag) return;
    const int tid = threadIdx.x;
    if (tid < 128) {
        const int s = p0 + tid;
        thresh_s[tid] = (s < nflag) ? (m1_arr[plist[s]] + CAND_MARGIN) : -3.0e38f;
    }

    const int lane = tid & 63;
    const int wid  = tid >> 6;
    const int wr = wid >> 1, wc = wid & 1;
    const int l15 = lane & 15, l4 = lane >> 4;

    const char* xhb = (const char*)xgt_hi + ((size_t)st << 16);
    const char* xlb = (const char*)xgt_lo + ((size_t)st << 16);
    const char* ehb = (const char*)et_hi + ((size_t)(kt << 2) << 14);
    const char* elb = (const char*)et_lo + ((size_t)(kt << 2) << 14);

    float4v acc[4][4];
    const float4v zero4 = {0.f, 0.f, 0.f, 0.f};
#pragma unroll
    for (int pf = 0; pf < 4; ++pf)
#pragma unroll
        for (int cf = 0; cf < 4; ++cf) acc[pf][cf] = zero4;

    for (int ct = 0; ct < 4; ++ct) {
        const int coff = ct << 14;
        __syncthreads();
#pragma unroll
        for (int i = 0; i < 4; ++i) {
            const int off = (((i << 2) + wid) << 10);
            const int src = off + (lane << 4);
            __builtin_amdgcn_global_load_lds((gvoid*)(xhb + coff + src),
                (lvoid*)((char*)xsb_hi + off), 16, 0, 0);
            __builtin_amdgcn_global_load_lds((gvoid*)(xlb + coff + src),
                (lvoid*)((char*)xsb_lo + off), 16, 0, 0);
            __builtin_amdgcn_global_load_lds((gvoid*)(ehb + coff + src),
                (lvoid*)((char*)esb_hi + off), 16, 0, 0);
            __builtin_amdgcn_global_load_lds((gvoid*)(elb + coff + src),
                (lvoid*)((char*)esb_lo + off), 16, 0, 0);
        }
        __syncthreads();
#pragma unroll
        for (int ks = 0; ks < 2; ++ks) {
            const int cgb = (ks << 2) + l4;
            const int ebase = (cgb << 7) + (wc << 6) + l15;
            const int xbase = (cgb << 7) + (wr << 6) + l15;
            bf16x8v eh[4], el[4];
#pragma unroll
            for (int cf = 0; cf < 4; ++cf) {
                const int eo = (ebase + (cf << 4)) << 3;
                eh[cf] = *(const bf16x8v*)(esb_hi + eo);
                el[cf] = *(const bf16x8v*)(esb_lo + eo);
            }
#pragma unroll
            for (int pf = 0; pf < 4; ++pf) {
                const int xo = (xbase + (pf << 4)) << 3;
                const bf16x8v xh = *(const bf16x8v*)(xsb_hi + xo);
                const bf16x8v xl = *(const bf16x8v*)(xsb_lo + xo);
#pragma unroll
                for (int cf = 0; cf < 4; ++cf) {
                    acc[pf][cf] = __builtin_amdgcn_mfma_f32_16x16x32_bf16(eh[cf], xh, acc[pf][cf], 0, 0, 0);
                    acc[pf][cf] = __builtin_amdgcn_mfma_f32_16x16x32_bf16(eh[cf], xl, acc[pf][cf], 0, 0, 0);
                    acc[pf][cf] = __builtin_amdgcn_mfma_f32_16x16x32_bf16(el[cf], xh, acc[pf][cf], 0, 0, 0);
                }
            }
        }
    }

    const int k0 = kt << 7;
#pragma unroll
    for (int cf = 0; cf < 4; ++cf) {
        const int kb = k0 + (wc << 6) + (cf << 4) + (l4 << 2);
        const float4v ev = *(const float4v*)(esq + kb);
#pragma unroll
        for (int pf = 0; pf < 4; ++pf) {
            const int slotl = (wr << 6) + (pf << 4) + l15;
            const int slotg = p0 + slotl;
            if (slotg < nflag) {
                const float th = thresh_s[slotl];
#pragma unroll
                for (int r = 0; r < 4; ++r) {
                    const float s = fmaf(-2.0f, acc[pf][cf][r], ev[r]);
                    if (s <= th) {
                        int pos = atomicAdd(ccount, 1);
                        if (pos < MAXCAND) cand[pos] = ((u32)slotg << 10) | (u32)(kb + r);
                    }
                }
            }
        }
    }
}

// ---------------------------------------------------------------------------
// Exact np rescore: one thread per candidate (unchanged).
// ---------------------------------------------------------------------------
__global__ __launch_bounds__(256) void vq_cand_np(const float* __restrict__ xg,
                                                  const float* __restrict__ emb,
                                                  const float* __restrict__ esq,
                                                  const float* __restrict__ xsq_arr,
                                                  const u32* __restrict__ cand,
                                                  const int* __restrict__ ccount,
                                                  u64* __restrict__ best_arr) {
    const int ncand = min(*ccount, MAXCAND);
    const int id = blockIdx.x * 256 + threadIdx.x;
    if (id >= ncand) return;
    const u32 v = cand[id];
    const int slot = (int)(v >> 10);
    const int k = (int)(v & 1023u);
    const float cr = np_einsum_dot_256(xg + (size_t)slot * C_, emb + (size_t)k * C_);
    const float d2 = fadd_x(fsub_x(xsq_arr[slot], fmul_x(2.0f, cr)), esq[k]);
    const u64 pk = ((u64)__float_as_uint(d2) << 32) | (unsigned)k;
    atomicMin(&best_arr[slot], pk);
}

__global__ __launch_bounds__(256) void finalize_kernel(const u64* __restrict__ best_arr,
                                                       const int* __restrict__ plist,
                                                       const int* __restrict__ pcount,
                                                       int* __restrict__ idx_arr) {
    const int nflag = min(*pcount, MAXFLAG);
    const int s = blockIdx.x * 256 + threadIdx.x;
    if (s >= nflag) return;
    idx_arr[plist[s]] = (int)(best_arr[s] & 0xffffffffu);
}

// ---------------------------------------------------------------------------
// gather + STE: out = fl(fl(q - x) + x). Runs LAST. (unchanged)
// ---------------------------------------------------------------------------
__global__ __launch_bounds__(256) void gather_kernel(const float* __restrict__ x,
                                                     const float* __restrict__ emb,
                                                     const int* __restrict__ idx_arr,
                                                     float* __restrict__ out) {
    __shared__ int idx_s[128];
    __shared__ float qs[32][257];
    const int tid = threadIdx.x;
    const int blk = blockIdx.x;
    const int b   = blk >> 3;
    const int hw0 = (blk & 7) << 7;
    if (tid < 128) idx_s[tid] = idx_arr[blk * 128 + tid];
    __syncthreads();
    const int cidx = tid >> 5;          // 0..7
    const int px   = tid & 31;          // 0..31
    for (int ch = 0; ch < 4; ++ch) {
        const int p0c = ch << 5;
#pragma unroll 8
        for (int r = 0; r < 32; ++r)
            qs[r][tid] = emb[(size_t)idx_s[p0c + r] * C_ + tid];
        __syncthreads();
#pragma unroll
        for (int j = 0; j < 32; ++j) {
            const int c = (j << 3) + cidx;
            const size_t o = ((size_t)b * C_ + c) * HW_ + hw0 + p0c + px;
            const float q  = qs[px][c];
            const float xv = x[o];
            out[o] = fadd_x(fsub_x(q, xv), xv);
        }
        __syncthreads();
    }
}

extern "C" void kernel_launch(void* const* d_in, const int* in_sizes, int n_in,
                              void* d_out, int out_size, void* d_ws, size_t ws_size,
                              hipStream_t stream) {
    const float* x   = (const float*)d_in[0];
    const float* emb = (const float*)d_in[1];
    float* out = (float*)d_out;
    char* ws = (char*)d_ws;

    float* esq     = (float*)ws;                 // 4 KB
    int*   pcount  = (int*)(ws + 4096);
    int*   ccount  = (int*)(ws + 8192);
    int*   plist   = (int*)(ws + 12288);         // 32 KB
    float* m1_arr  = (float*)(ws + 65536);       // 256 KB
    int*   idx_arr = (int*)(ws + 327680);        // 256 KB
    float* xsq_arr = (float*)(ws + 589824);      // 32 KB
    u64*   best_arr= (u64*)(ws + 622592);        // 64 KB
    u32*   cand    = (u32*)(ws + 688128);        // 256 KB
    u16*   et_hi   = (u16*)(ws + 983040);        // 512 KB (tiled layout)
    u16*   et_lo   = (u16*)(ws + 1507328);       // 512 KB (total ws ~2 MB)

    // xt hi/lo tiled planes fill the 64 MB output buffer; consumed by vq_main.
    u16* xt_hi = (u16*)d_out;
    u16* xt_lo = (u16*)d_out + 16777216;
    // After vq_main, the out buffer is free until gather: xg + xgt live there.
    float* xg      = (float*)d_out;                           // 8 MB
    u16*   xgt_hi  = (u16*)((char*)d_out + (8u << 20));       // 4 MB
    u16*   xgt_lo  = (u16*)((char*)d_out + (12u << 20));      // 4 MB

    zero_kernel<<<1, 256, 0, stream>>>(pcount, ccount);
    esq_np_kernel<<<K_ / 256, 256, 0, stream>>>(emb, esq);
    cvt_e_kernel<<<K_ / 32, 256, 0, stream>>>(emb, et_hi, et_lo);
    cvt_x_kernel<<<NPIX / 32, 256, 0, stream>>>(x, xt_hi, xt_lo);
    vq_main_mfma<<<NPIX / 64, 512, 0, stream>>>(xt_hi, xt_lo, et_hi, et_lo, esq,
                                                idx_arr, m1_arr, plist, pcount);
    gather_x_kernel<<<MAXFLAG, 256, 0, stream>>>(x, plist, pcount, xg, xsq_arr, best_arr);
    cvt_xg_kernel<<<MAXFLAG / 32, 256, 0, stream>>>(xg, pcount, xgt_hi, xgt_lo);
    vq_scan_mfma<<<(MAXFLAG / 128) * 8, 256, 0, stream>>>(xgt_hi, xgt_lo, et_hi, et_lo,
                                                          esq, m1_arr, plist, pcount,
                                                          cand, ccount);
    vq_cand_np<<<MAXCAND / 256, 256, 0, stream>>>(xg, emb, esq, xsq_arr, cand, ccount,
                                                  best_arr);
    finalize_kernel<<<MAXFLAG / 256, 256, 0, stream>>>(best_arr, plist, pcount, idx_arr);
    gather_kernel<<<NPIX / 128, 256, 0, stream>>>(x, emb, idx_arr, out);
}

// Round 13
// 359.317 us; speedup vs baseline: 1.1126x; 1.1126x over previous
//
#include <hip/hip_runtime.h>

#define B_    64
#define C_    256
#define HW_   1024
#define NPIX  (B_ * HW_)
#define K_    1024
#define TAU_FLAG    2.0e-4f
#define CAND_MARGIN 2.2e-4f
#define MAXFLAG     8192
#define MAXCAND     65536

typedef unsigned short u16;
typedef unsigned int   u32;
typedef unsigned long long u64;
typedef __attribute__((ext_vector_type(8))) __bf16 bf16x8v;
typedef __attribute__((ext_vector_type(4))) float  float4v;
typedef __attribute__((address_space(1))) void gvoid;
typedef __attribute__((address_space(3))) void lvoid;

// Rounding barriers: force a separately-rounded f32 mul/add/sub (defeat
// -ffp-contract=fast fusion and any reassociation across the boundary).
__device__ __forceinline__ float fmul_x(float a, float b) { float p = a * b; asm volatile("" : "+v"(p)); return p; }
__device__ __forceinline__ float fadd_x(float a, float b) { float s = a + b; asm volatile("" : "+v"(s)); return s; }
__device__ __forceinline__ float fsub_x(float a, float b) { float s = a - b; asm volatile("" : "+v"(s)); return s; }

// f32 -> bf16 round-to-nearest-even (finite inputs only), and back.
__device__ __forceinline__ u16 bf16_rne(float f) {
    u32 u = __float_as_uint(f);
    u32 r = u + 0x7FFFu + ((u >> 16) & 1u);
    return (u16)(r >> 16);
}
__device__ __forceinline__ float bf16_to_f(u16 h) { return __uint_as_float(((u32)h) << 16); }

__device__ __forceinline__ uint4 pack8(const u16* h) {
    return make_uint4((u32)h[0] | ((u32)h[1] << 16), (u32)h[2] | ((u32)h[3] << 16),
                      (u32)h[4] | ((u32)h[5] << 16), (u32)h[6] | ((u32)h[7] << 16));
}

// ---------------------------------------------------------------------------
// numpy pairwise sum replica for 256 contiguous squares (unchanged).
// ---------------------------------------------------------------------------
__device__ __forceinline__ float np_sumsq_256(const float* __restrict__ a) {
    float half[2];
#pragma unroll
    for (int h = 0; h < 2; ++h) {
        const float* p = a + h * 128;
        float r[8];
#pragma unroll
        for (int j = 0; j < 8; ++j) r[j] = fmul_x(p[j], p[j]);
        for (int i = 8; i < 128; i += 8)
#pragma unroll
            for (int j = 0; j < 8; ++j) r[j] = fadd_x(r[j], fmul_x(p[i + j], p[i + j]));
        half[h] = fadd_x(fadd_x(fadd_x(r[0], r[1]), fadd_x(r[2], r[3])),
                         fadd_x(fadd_x(r[4], r[5]), fadd_x(r[6], r[7])));
    }
    return fadd_x(half[0], half[1]);
}

// ---------------------------------------------------------------------------
// numpy einsum f32 dot replica (unchanged).
// ---------------------------------------------------------------------------
__device__ float np_einsum_dot_256(const float* __restrict__ xr,
                                   const float* __restrict__ er) {
    float acc0 = 0.f, acc1 = 0.f, acc2 = 0.f, acc3 = 0.f;
    for (int blk = 0; blk < 256; blk += 16) {
#pragma unroll
        for (int sub = 3; sub >= 0; --sub) {
            const int base = blk + sub * 4;
            acc0 = fadd_x(acc0, fmul_x(xr[base + 0], er[base + 0]));
            acc1 = fadd_x(acc1, fmul_x(xr[base + 1], er[base + 1]));
            acc2 = fadd_x(acc2, fmul_x(xr[base + 2], er[base + 2]));
            acc3 = fadd_x(acc3, fmul_x(xr[base + 3], er[base + 3]));
        }
    }
    return fadd_x(fadd_x(acc0, acc2), fadd_x(acc1, acc3));
}

// ---------------------------------------------------------------------------
__global__ __launch_bounds__(256) void zero_kernel(int* pcount, int* ccount) {
    if (threadIdx.x == 0 && blockIdx.x == 0) { *pcount = 0; *ccount = 0; }
}

// e_sq via numpy-pairwise replica (unchanged).
__global__ __launch_bounds__(256) void esq_np_kernel(const float* __restrict__ emb,
                                                     float* __restrict__ esq) {
    const int k = blockIdx.x * 256 + threadIdx.x;
    esq[k] = np_sumsq_256(emb + (size_t)k * C_);
}

// ---------------------------------------------------------------------------
// emb f32 -> hi/lo bf16 planes in STAGED-TILE layout (unchanged):
// chunk (kb*4+ct) is 16KB/plane: [cg8][128][8].
// ---------------------------------------------------------------------------
__global__ __launch_bounds__(256) void cvt_e_kernel(const float* __restrict__ emb,
                                                    u16* __restrict__ et_hi,
                                                    u16* __restrict__ et_lo) {
    const int tid = threadIdx.x;
    const int k  = (blockIdx.x << 5) + (tid & 31);
    const int cg = tid >> 5;
    const int kb = k >> 7;
    const int kr = k & 127;
#pragma unroll
    for (int ct = 0; ct < 4; ++ct) {
        const int c = (ct << 6) + (cg << 3);
        const float* src = emb + (size_t)k * C_ + c;
        u16 h[8], l[8];
#pragma unroll
        for (int i = 0; i < 8; ++i) {
            const float f = src[i];
            h[i] = bf16_rne(f);
            l[i] = bf16_rne(f - bf16_to_f(h[i]));
        }
        const size_t off = ((size_t)((kb << 2) + ct) << 13) + (cg << 10) + (kr << 3);
        *(uint4*)(et_hi + off) = pack8(h);
        *(uint4*)(et_lo + off) = pack8(l);
    }
}

// ---------------------------------------------------------------------------
// x f32 -> hi/lo bf16 planes in 64-ROW chunk layout (unchanged):
// chunk (pb*4+ct) is 8KB/plane: [cg8][row64][8].
// ---------------------------------------------------------------------------
__global__ __launch_bounds__(256) void cvt_x_kernel(const float* __restrict__ x,
                                                    u16* __restrict__ xt_hi,
                                                    u16* __restrict__ xt_lo) {
    __shared__ float xs[256][36];       // [c][px(32)+pad]
    const int tid = threadIdx.x;
    const int pix0 = blockIdx.x << 5;   // 32 pixels per block
    const int b   = pix0 >> 10;
    const int hw0 = pix0 & 1023;
#pragma unroll
    for (int r8 = 0; r8 < 8; ++r8) {
        const int u = (r8 << 8) + tid;  // 0..2047 float4s
        const int c = u >> 3;
        const int hq = (u & 7) << 2;
        const float4 v = *(const float4*)(x + ((size_t)b * C_ + c) * HW_ + hw0 + hq);
        *(float4*)&xs[c][hq] = v;
    }
    __syncthreads();
    const int cg = tid >> 5;            // 0..7
    const int px = tid & 31;            // 0..31
    const int pb = pix0 >> 6;           // 64-px chunk index
    const int r  = (pix0 & 63) + px;    // row within chunk
#pragma unroll
    for (int ct = 0; ct < 4; ++ct) {
        const int c = (ct << 6) + (cg << 3);
        u16 h[8], l[8];
#pragma unroll
        for (int i = 0; i < 8; ++i) {
            const float f = xs[c + i][px];
            h[i] = bf16_rne(f);
            l[i] = bf16_rne(f - bf16_to_f(h[i]));
        }
        const size_t off = ((size_t)((pb << 2) + ct) << 12) + (cg << 9) + (r << 3);
        *(uint4*)(xt_hi + off) = pack8(h);
        *(uint4*)(xt_lo + off) = pack8(l);
    }
}

// ---------------------------------------------------------------------------
// MFMA bf16x3 scoring + top-2 + flag. Verbatim round-8 kernel (measured 131
// us, the empirical optimum of 5 structural variants) + bijective XCD
// swizzle (nwg=1024 % 8 == 0) — pure block->pixel permutation.
// 512 threads (8 waves, 2x4 wave grid), 64 px x 1024 codes per block.
// LDS 80KB = x_hi 32K + x_lo 32K (persistent) + single 16KB e-buffer.
// 2 blocks/CU = 16 waves/CU; cross-block overlap hides stage drains.
// Scores bitwise identical to rounds 2-12.
// ---------------------------------------------------------------------------
__global__ __launch_bounds__(512, 4) void vq_main_mfma(const u16* __restrict__ xt_hi,
                                                       const u16* __restrict__ xt_lo,
                                                       const u16* __restrict__ et_hi,
                                                       const u16* __restrict__ et_lo,
                                                       const float* __restrict__ esq,
                                                       int* __restrict__ idx_arr,
                                                       float* __restrict__ m1_arr,
                                                       int* __restrict__ plist,
                                                       int* __restrict__ pcount) {
    __shared__ __align__(16) char smem[81920];
    // XH [ct4][cg8][row64][8] @0; XL @32768; E @65536 (hi 8KB, lo 8KB)
    float* r_m1 = (float*)(smem + 65536);   // aliases E after the k-loop
    float* r_m2 = (float*)(smem + 69888);
    int*   r_i1 = (int*)(smem + 74240);

    const int tid  = threadIdx.x;
    const int lane = tid & 63;
    const int wid  = tid >> 6;        // 0..7
    const int wr   = wid >> 2;        // 0..1 (pixel half)
    const int wc   = wid & 3;         // 0..3 (code quarter)
    const int l15 = lane & 15, l4 = lane >> 4;
    // bijective XCD swizzle: consecutive-on-XCD blocks share the E stream
    const int bid = blockIdx.x;
    const int swz = ((bid & 7) << 7) + (bid >> 3);
    const int p0 = swz * 64;

    const char* xhb = (const char*)xt_hi + ((size_t)swz << 15); // 32KB/block
    const char* xlb = (const char*)xt_lo + ((size_t)swz << 15);

    // prologue: stage persistent x (hi+lo), linear copy (global layout == LDS)
#pragma unroll
    for (int i = 0; i < 4; ++i) {
        const int seg = (i << 3) + wid;     // 0..31, wave-uniform
        __builtin_amdgcn_global_load_lds((gvoid*)(xhb + (seg << 10) + (lane << 4)),
            (lvoid*)(smem + (seg << 10)), 16, 0, 0);
        __builtin_amdgcn_global_load_lds((gvoid*)(xlb + (seg << 10) + (lane << 4)),
            (lvoid*)(smem + 32768 + (seg << 10)), 16, 0, 0);
    }

    float m1[2], m2[2]; int i1[2];
#pragma unroll
    for (int i = 0; i < 2; ++i) { m1[i] = 3.0e38f; m2[i] = 3.0e38f; i1[i] = 0; }

    for (int kt = 0; kt < 8; ++kt) {
        float4v acc[2][2];
        const float4v zero4 = {0.f, 0.f, 0.f, 0.f};
#pragma unroll
        for (int pf = 0; pf < 2; ++pf)
#pragma unroll
            for (int cf = 0; cf < 2; ++cf) acc[pf][cf] = zero4;

        for (int kg = 0; kg < 8; ++kg) {    // 32-channel steps, ascending
            __syncthreads();                // E free (prev step consumed); x ready @step0
            {   // stage E: 8KB hi + 8KB lo, 2 loads/wave
                const size_t ch = (((size_t)((kt << 2) + (kg >> 1))) << 14) + ((size_t)(kg & 1) << 13);
                __builtin_amdgcn_global_load_lds(
                    (gvoid*)((const char*)et_hi + ch + (wid << 10) + (lane << 4)),
                    (lvoid*)(smem + 65536 + (wid << 10)), 16, 0, 0);
                __builtin_amdgcn_global_load_lds(
                    (gvoid*)((const char*)et_lo + ch + (wid << 10) + (lane << 4)),
                    (lvoid*)(smem + 65536 + 8192 + (wid << 10)), 16, 0, 0);
            }
            __syncthreads();                // E landed (vmcnt drained by all waves)

            bf16x8v eh[2], el[2];
#pragma unroll
            for (int cf = 0; cf < 2; ++cf) {
                const int eo = 65536 + (l4 << 11) + (((wc << 5) + (cf << 4) + l15) << 4);
                eh[cf] = *(const bf16x8v*)(smem + eo);
                el[cf] = *(const bf16x8v*)(smem + 8192 + eo);
            }
            const int ct = kg >> 1;
            const int cg = ((kg & 1) << 2) + l4;
#pragma unroll
            for (int pf = 0; pf < 2; ++pf) {
                const int xo = (ct << 13) + (cg << 10) + (((wr << 5) + (pf << 4) + l15) << 4);
                const bf16x8v xh = *(const bf16x8v*)(smem + xo);
                const bf16x8v xl = *(const bf16x8v*)(smem + 32768 + xo);
#pragma unroll
                for (int cf = 0; cf < 2; ++cf) {
                    acc[pf][cf] = __builtin_amdgcn_mfma_f32_16x16x32_bf16(eh[cf], xh, acc[pf][cf], 0, 0, 0);
                    acc[pf][cf] = __builtin_amdgcn_mfma_f32_16x16x32_bf16(eh[cf], xl, acc[pf][cf], 0, 0, 0);
                    acc[pf][cf] = __builtin_amdgcn_mfma_f32_16x16x32_bf16(el[cf], xh, acc[pf][cf], 0, 0, 0);
                }
            }
        }
        // top-2 update; k ascending per pixel slot (cf outer, reg inner)
        const int k0 = kt << 7;
#pragma unroll
        for (int cf = 0; cf < 2; ++cf) {
            const int kb = k0 + (wc << 5) + (cf << 4) + (l4 << 2);
            const float4v ev = *(const float4v*)(esq + kb);
#pragma unroll
            for (int pf = 0; pf < 2; ++pf) {
#pragma unroll
                for (int r = 0; r < 4; ++r) {
                    const float s = fmaf(-2.0f, acc[pf][cf][r], ev[r]);
                    const int k = kb + r;
                    if (s < m1[pf])      { m2[pf] = m1[pf]; m1[pf] = s; i1[pf] = k; }
                    else if (s < m2[pf]) { m2[pf] = s; }
                }
            }
        }
    }

    __syncthreads();    // all E reads done; alias reduction arrays
#pragma unroll
    for (int pf = 0; pf < 2; ++pf) {
        const int p = (wr << 5) + (pf << 4) + l15;   // 0..63
        const int slot = (wc << 2) + l4;             // 0..15
        r_m1[p * 17 + slot] = m1[pf]; r_m2[p * 17 + slot] = m2[pf]; r_i1[p * 17 + slot] = i1[pf];
    }
    __syncthreads();
    if (tid < 64) {
        const int p = tid;
        float M1 = r_m1[p * 17 + 0], M2 = r_m2[p * 17 + 0];
        int   I1 = r_i1[p * 17 + 0];
        for (int t = 1; t < 16; ++t) {
            const float a1 = r_m1[p * 17 + t], a2 = r_m2[p * 17 + t];
            const int   ai = r_i1[p * 17 + t];
            if (a1 < M1 || (a1 == M1 && ai < I1)) { M2 = fminf(M1, a2); M1 = a1; I1 = ai; }
            else                                  { M2 = fminf(M2, a1); }
        }
        const int pix = p0 + p;
        idx_arr[pix] = I1;
        m1_arr[pix] = M1;
        if (M2 - M1 <= TAU_FLAG) {
            int pos = atomicAdd(pcount, 1);
            if (pos < MAXFLAG) plist[pos] = pix;
        }
    }
}

// ---------------------------------------------------------------------------
// gather_x v2: 8 flagged slots per block (grid MAXFLAG/8 = 1024).
// - 8x MLP on the scattered x-column loads (independent unrolled loads).
// - Per-slot numpy-pairwise sumsq: identical 16-chain tree + combine order.
// - Emits xg (f32, for cand rescore), xsq, best-init, AND the bf16 xgt
//   tiles directly from LDS (same bf16_rne, same 128-row chunk layout) —
//   the separate cvt_xg kernel and its xg re-read are eliminated.
// LDS stride 264 floats: sumsq-phase banks (8p+j) all-distinct, 2-way max.
// ---------------------------------------------------------------------------
__global__ __launch_bounds__(256) void gather_x_kernel(const float* __restrict__ x,
                                                       const int* __restrict__ plist,
                                                       const int* __restrict__ pcount,
                                                       float* __restrict__ xg,
                                                       float* __restrict__ xsq_arr,
                                                       u64* __restrict__ best_arr,
                                                       u16* __restrict__ xgt_hi,
                                                       u16* __restrict__ xgt_lo) {
    __shared__ float xs[8][264];
    __shared__ float rsum[8][16];
    __shared__ int pix_s[8];
    const int nflag = min(*pcount, MAXFLAG);
    const int sbase = blockIdx.x << 3;
    if (sbase >= nflag) return;
    const int nact = min(8, nflag - sbase);
    const int tid = threadIdx.x;

    if (tid < 8) pix_s[tid] = (tid < nact) ? plist[sbase + tid] : plist[sbase];
    __syncthreads();
#pragma unroll
    for (int p = 0; p < 8; ++p) {       // 8 independent scattered loads in flight
        const int pix = pix_s[p];
        const int b = pix >> 10, hw = pix & 1023;
        const float v = x[((size_t)(b * C_ + tid)) * HW_ + hw];
        xs[p][tid] = v;
        if (p < nact) xg[(size_t)(sbase + p) * C_ + tid] = v;
    }
    __syncthreads();
    if (tid < 128) {                    // 8 slots x 16 chains, exact np tree
        const int p = tid >> 4, h = (tid >> 3) & 1, j = tid & 7;
        const float* q = &xs[p][h * 128];
        float r = fmul_x(q[j], q[j]);
        for (int i = 8; i < 128; i += 8) r = fadd_x(r, fmul_x(q[i + j], q[i + j]));
        rsum[p][h * 8 + j] = r;
    }
    __syncthreads();
    if (tid < 8 && tid < nact) {
        const float* r0 = &rsum[tid][0];
        const float h0 = fadd_x(fadd_x(fadd_x(r0[0], r0[1]), fadd_x(r0[2], r0[3])),
                                fadd_x(fadd_x(r0[4], r0[5]), fadd_x(r0[6], r0[7])));
        const float h1 = fadd_x(fadd_x(fadd_x(r0[8], r0[9]), fadd_x(r0[10], r0[11])),
                                fadd_x(fadd_x(r0[12], r0[13]), fadd_x(r0[14], r0[15])));
        xsq_arr[sbase + tid] = fadd_x(h0, h1);
        best_arr[sbase + tid] = ~0ull;
    }
    // emit bf16 staged tiles (replaces cvt_xg; identical values & layout)
    {
        const int p  = tid >> 5;            // 0..7
        const int ct = (tid >> 3) & 3;      // 0..3
        const int cg = tid & 7;             // 0..7
        if (p < nact) {
            const int s  = sbase + p;
            const int sb = s >> 7;
            const int sr = s & 127;
            const int c = (ct << 6) + (cg << 3);
            u16 h[8], l[8];
#pragma unroll
            for (int i = 0; i < 8; ++i) {
                const float f = xs[p][c + i];
                h[i] = bf16_rne(f);
                l[i] = bf16_rne(f - bf16_to_f(h[i]));
            }
            const size_t off = ((size_t)((sb << 2) + ct) << 13) + (cg << 10) + (sr << 3);
            *(uint4*)(xgt_hi + off) = pack8(h);
            *(uint4*)(xgt_lo + off) = pack8(l);
        }
    }
}

// ---------------------------------------------------------------------------
// MFMA scan of flagged slots (unchanged): 128 slots x 128 codes per block;
// candidates appended to a global list.
// ---------------------------------------------------------------------------
__global__ __launch_bounds__(256) void vq_scan_mfma(const u16* __restrict__ xgt_hi,
                                                    const u16* __restrict__ xgt_lo,
                                                    const u16* __restrict__ et_hi,
                                                    const u16* __restrict__ et_lo,
                                                    const float* __restrict__ esq,
                                                    const float* __restrict__ m1_arr,
                                                    const int* __restrict__ plist,
                                                    const int* __restrict__ pcount,
                                                    u32* __restrict__ cand,
                                                    int* __restrict__ ccount) {
    __shared__ __align__(16) u16 xsb_hi[8192], xsb_lo[8192], esb_hi[8192], esb_lo[8192];
    __shared__ float thresh_s[128];

    const int nflag = min(*pcount, MAXFLAG);
    const int st = blockIdx.x >> 3;     // slot tile
    const int kt = blockIdx.x & 7;      // code tile
    const int p0 = st << 7;
    if (p0 >= nflag) return;
    const int tid = threadIdx.x;
    if (tid < 128) {
        const int s = p0 + tid;
        thresh_s[tid] = (s < nflag) ? (m1_arr[plist[s]] + CAND_MARGIN) : -3.0e38f;
    }

    const int lane = tid & 63;
    const int wid  = tid >> 6;
    const int wr = wid >> 1, wc = wid & 1;
    const int l15 = lane & 15, l4 = lane >> 4;

    const char* xhb = (const char*)xgt_hi + ((size_t)st << 16);
    const char* xlb = (const char*)xgt_lo + ((size_t)st << 16);
    const char* ehb = (const char*)et_hi + ((size_t)(kt << 2) << 14);
    const char* elb = (const char*)et_lo + ((size_t)(kt << 2) << 14);

    float4v acc[4][4];
    const float4v zero4 = {0.f, 0.f, 0.f, 0.f};
#pragma unroll
    for (int pf = 0; pf < 4; ++pf)
#pragma unroll
        for (int cf = 0; cf < 4; ++cf) acc[pf][cf] = zero4;

    for (int ct = 0; ct < 4; ++ct) {
        const int coff = ct << 14;
        __syncthreads();
#pragma unroll
        for (int i = 0; i < 4; ++i) {
            const int off = (((i << 2) + wid) << 10);
            const int src = off + (lane << 4);
            __builtin_amdgcn_global_load_lds((gvoid*)(xhb + coff + src),
                (lvoid*)((char*)xsb_hi + off), 16, 0, 0);
            __builtin_amdgcn_global_load_lds((gvoid*)(xlb + coff + src),
                (lvoid*)((char*)xsb_lo + off), 16, 0, 0);
            __builtin_amdgcn_global_load_lds((gvoid*)(ehb + coff + src),
                (lvoid*)((char*)esb_hi + off), 16, 0, 0);
            __builtin_amdgcn_global_load_lds((gvoid*)(elb + coff + src),
                (lvoid*)((char*)esb_lo + off), 16, 0, 0);
        }
        __syncthreads();
#pragma unroll
        for (int ks = 0; ks < 2; ++ks) {
            const int cgb = (ks << 2) + l4;
            const int ebase = (cgb << 7) + (wc << 6) + l15;
            const int xbase = (cgb << 7) + (wr << 6) + l15;
            bf16x8v eh[4], el[4];
#pragma unroll
            for (int cf = 0; cf < 4; ++cf) {
                const int eo = (ebase + (cf << 4)) << 3;
                eh[cf] = *(const bf16x8v*)(esb_hi + eo);
                el[cf] = *(const bf16x8v*)(esb_lo + eo);
            }
#pragma unroll
            for (int pf = 0; pf < 4; ++pf) {
                const int xo = (xbase + (pf << 4)) << 3;
                const bf16x8v xh = *(const bf16x8v*)(xsb_hi + xo);
                const bf16x8v xl = *(const bf16x8v*)(xsb_lo + xo);
#pragma unroll
                for (int cf = 0; cf < 4; ++cf) {
                    acc[pf][cf] = __builtin_amdgcn_mfma_f32_16x16x32_bf16(eh[cf], xh, acc[pf][cf], 0, 0, 0);
                    acc[pf][cf] = __builtin_amdgcn_mfma_f32_16x16x32_bf16(eh[cf], xl, acc[pf][cf], 0, 0, 0);
                    acc[pf][cf] = __builtin_amdgcn_mfma_f32_16x16x32_bf16(el[cf], xh, acc[pf][cf], 0, 0, 0);
                }
            }
        }
    }

    const int k0 = kt << 7;
#pragma unroll
    for (int cf = 0; cf < 4; ++cf) {
        const int kb = k0 + (wc << 6) + (cf << 4) + (l4 << 2);
        const float4v ev = *(const float4v*)(esq + kb);
#pragma unroll
        for (int pf = 0; pf < 4; ++pf) {
            const int slotl = (wr << 6) + (pf << 4) + l15;
            const int slotg = p0 + slotl;
            if (slotg < nflag) {
                const float th = thresh_s[slotl];
#pragma unroll
                for (int r = 0; r < 4; ++r) {
                    const float s = fmaf(-2.0f, acc[pf][cf][r], ev[r]);
                    if (s <= th) {
                        int pos = atomicAdd(ccount, 1);
                        if (pos < MAXCAND) cand[pos] = ((u32)slotg << 10) | (u32)(kb + r);
                    }
                }
            }
        }
    }
}

// ---------------------------------------------------------------------------
// Exact np rescore: one thread per candidate (unchanged).
// ---------------------------------------------------------------------------
__global__ __launch_bounds__(256) void vq_cand_np(const float* __restrict__ xg,
                                                  const float* __restrict__ emb,
                                                  const float* __restrict__ esq,
                                                  const float* __restrict__ xsq_arr,
                                                  const u32* __restrict__ cand,
                                                  const int* __restrict__ ccount,
                                                  u64* __restrict__ best_arr) {
    const int ncand = min(*ccount, MAXCAND);
    const int id = blockIdx.x * 256 + threadIdx.x;
    if (id >= ncand) return;
    const u32 v = cand[id];
    const int slot = (int)(v >> 10);
    const int k = (int)(v & 1023u);
    const float cr = np_einsum_dot_256(xg + (size_t)slot * C_, emb + (size_t)k * C_);
    const float d2 = fadd_x(fsub_x(xsq_arr[slot], fmul_x(2.0f, cr)), esq[k]);
    const u64 pk = ((u64)__float_as_uint(d2) << 32) | (unsigned)k;
    atomicMin(&best_arr[slot], pk);
}

__global__ __launch_bounds__(256) void finalize_kernel(const u64* __restrict__ best_arr,
                                                       const int* __restrict__ plist,
                                                       const int* __restrict__ pcount,
                                                       int* __restrict__ idx_arr) {
    const int nflag = min(*pcount, MAXFLAG);
    const int s = blockIdx.x * 256 + threadIdx.x;
    if (s >= nflag) return;
    idx_arr[plist[s]] = (int)(best_arr[s] & 0xffffffffu);
}

// ---------------------------------------------------------------------------
// gather + STE: out = fl(fl(q - x) + x). Runs LAST. (unchanged)
// ---------------------------------------------------------------------------
__global__ __launch_bounds__(256) void gather_kernel(const float* __restrict__ x,
                                                     const float* __restrict__ emb,
                                                     const int* __restrict__ idx_arr,
                                                     float* __restrict__ out) {
    __shared__ int idx_s[128];
    __shared__ float qs[32][257];
    const int tid = threadIdx.x;
    const int blk = blockIdx.x;
    const int b   = blk >> 3;
    const int hw0 = (blk & 7) << 7;
    if (tid < 128) idx_s[tid] = idx_arr[blk * 128 + tid];
    __syncthreads();
    const int cidx = tid >> 5;          // 0..7
    const int px   = tid & 31;          // 0..31
    for (int ch = 0; ch < 4; ++ch) {
        const int p0c = ch << 5;
#pragma unroll 8
        for (int r = 0; r < 32; ++r)
            qs[r][tid] = emb[(size_t)idx_s[p0c + r] * C_ + tid];
        __syncthreads();
#pragma unroll
        for (int j = 0; j < 32; ++j) {
            const int c = (j << 3) + cidx;
            const size_t o = ((size_t)b * C_ + c) * HW_ + hw0 + p0c + px;
            const float q  = qs[px][c];
            const float xv = x[o];
            out[o] = fadd_x(fsub_x(q, xv), xv);
        }
        __syncthreads();
    }
}

extern "C" void kernel_launch(void* const* d_in, const int* in_sizes, int n_in,
                              void* d_out, int out_size, void* d_ws, size_t ws_size,
                              hipStream_t stream) {
    const float* x   = (const float*)d_in[0];
    const float* emb = (const float*)d_in[1];
    float* out = (float*)d_out;
    char* ws = (char*)d_ws;

    float* esq     = (float*)ws;                 // 4 KB
    int*   pcount  = (int*)(ws + 4096);
    int*   ccount  = (int*)(ws + 8192);
    int*   plist   = (int*)(ws + 12288);         // 32 KB
    float* m1_arr  = (float*)(ws + 65536);       // 256 KB
    int*   idx_arr = (int*)(ws + 327680);        // 256 KB
    float* xsq_arr = (float*)(ws + 589824);      // 32 KB
    u64*   best_arr= (u64*)(ws + 622592);        // 64 KB
    u32*   cand    = (u32*)(ws + 688128);        // 256 KB
    u16*   et_hi   = (u16*)(ws + 983040);        // 512 KB (tiled layout)
    u16*   et_lo   = (u16*)(ws + 1507328);       // 512 KB (total ws ~2 MB)

    // xt hi/lo tiled planes fill the 64 MB output buffer; consumed by vq_main.
    u16* xt_hi = (u16*)d_out;
    u16* xt_lo = (u16*)d_out + 16777216;
    // After vq_main, the out buffer is free until gather: xg + xgt live there.
    float* xg      = (float*)d_out;                           // 8 MB
    u16*   xgt_hi  = (u16*)((char*)d_out + (8u << 20));       // 4 MB
    u16*   xgt_lo  = (u16*)((char*)d_out + (12u << 20));      // 4 MB

    zero_kernel<<<1, 256, 0, stream>>>(pcount, ccount);
    esq_np_kernel<<<K_ / 256, 256, 0, stream>>>(emb, esq);
    cvt_e_kernel<<<K_ / 32, 256, 0, stream>>>(emb, et_hi, et_lo);
    cvt_x_kernel<<<NPIX / 32, 256, 0, stream>>>(x, xt_hi, xt_lo);
    vq_main_mfma<<<NPIX / 64, 512, 0, stream>>>(xt_hi, xt_lo, et_hi, et_lo, esq,
                                                idx_arr, m1_arr, plist, pcount);
    gather_x_kernel<<<MAXFLAG / 8, 256, 0, stream>>>(x, plist, pcount, xg, xsq_arr,
                                                     best_arr, xgt_hi, xgt_lo);
    vq_scan_mfma<<<(MAXFLAG / 128) * 8, 256, 0, stream>>>(xgt_hi, xgt_lo, et_hi, et_lo,
                                                          esq, m1_arr, plist, pcount,
                                                          cand, ccount);
    vq_cand_np<<<MAXCAND / 256, 256, 0, stream>>>(xg, emb, esq, xsq_arr, cand, ccount,
                                                  best_arr);
    finalize_kernel<<<MAXFLAG / 256, 256, 0, stream>>>(best_arr, plist, pcount, idx_arr);
    gather_kernel<<<NPIX / 128, 256, 0, stream>>>(x, emb, idx_arr, out);
}

// Round 14
// 338.568 us; speedup vs baseline: 1.1808x; 1.0613x over previous
//
#include <hip/hip_runtime.h>

#define B_    64
#define C_    256
#define HW_   1024
#define NPIX  (B_ * HW_)
#define K_    1024
#define TAU_FLAG    2.0e-4f
#define CAND_MARGIN 2.2e-4f
#define MAXFLAG     8192
#define MAXCAND     65536

typedef unsigned short u16;
typedef unsigned int   u32;
typedef unsigned long long u64;
typedef __attribute__((ext_vector_type(8))) __bf16 bf16x8v;
typedef __attribute__((ext_vector_type(4))) float  float4v;
typedef __attribute__((address_space(1))) void gvoid;
typedef __attribute__((address_space(3))) void lvoid;

// Rounding barriers: force a separately-rounded f32 mul/add/sub (defeat
// -ffp-contract=fast fusion and any reassociation across the boundary).
__device__ __forceinline__ float fmul_x(float a, float b) { float p = a * b; asm volatile("" : "+v"(p)); return p; }
__device__ __forceinline__ float fadd_x(float a, float b) { float s = a + b; asm volatile("" : "+v"(s)); return s; }
__device__ __forceinline__ float fsub_x(float a, float b) { float s = a - b; asm volatile("" : "+v"(s)); return s; }

// f32 -> bf16 round-to-nearest-even (finite inputs only), and back.
__device__ __forceinline__ u16 bf16_rne(float f) {
    u32 u = __float_as_uint(f);
    u32 r = u + 0x7FFFu + ((u >> 16) & 1u);
    return (u16)(r >> 16);
}
__device__ __forceinline__ float bf16_to_f(u16 h) { return __uint_as_float(((u32)h) << 16); }

__device__ __forceinline__ uint4 pack8(const u16* h) {
    return make_uint4((u32)h[0] | ((u32)h[1] << 16), (u32)h[2] | ((u32)h[3] << 16),
                      (u32)h[4] | ((u32)h[5] << 16), (u32)h[6] | ((u32)h[7] << 16));
}

// ---------------------------------------------------------------------------
// numpy pairwise sum replica for 256 contiguous squares (unchanged).
// ---------------------------------------------------------------------------
__device__ __forceinline__ float np_sumsq_256(const float* __restrict__ a) {
    float half[2];
#pragma unroll
    for (int h = 0; h < 2; ++h) {
        const float* p = a + h * 128;
        float r[8];
#pragma unroll
        for (int j = 0; j < 8; ++j) r[j] = fmul_x(p[j], p[j]);
        for (int i = 8; i < 128; i += 8)
#pragma unroll
            for (int j = 0; j < 8; ++j) r[j] = fadd_x(r[j], fmul_x(p[i + j], p[i + j]));
        half[h] = fadd_x(fadd_x(fadd_x(r[0], r[1]), fadd_x(r[2], r[3])),
                         fadd_x(fadd_x(r[4], r[5]), fadd_x(r[6], r[7])));
    }
    return fadd_x(half[0], half[1]);
}

// ---------------------------------------------------------------------------
// numpy einsum f32 dot replica (unchanged).
// ---------------------------------------------------------------------------
__device__ float np_einsum_dot_256(const float* __restrict__ xr,
                                   const float* __restrict__ er) {
    float acc0 = 0.f, acc1 = 0.f, acc2 = 0.f, acc3 = 0.f;
    for (int blk = 0; blk < 256; blk += 16) {
#pragma unroll
        for (int sub = 3; sub >= 0; --sub) {
            const int base = blk + sub * 4;
            acc0 = fadd_x(acc0, fmul_x(xr[base + 0], er[base + 0]));
            acc1 = fadd_x(acc1, fmul_x(xr[base + 1], er[base + 1]));
            acc2 = fadd_x(acc2, fmul_x(xr[base + 2], er[base + 2]));
            acc3 = fadd_x(acc3, fmul_x(xr[base + 3], er[base + 3]));
        }
    }
    return fadd_x(fadd_x(acc0, acc2), fadd_x(acc1, acc3));
}

// ---------------------------------------------------------------------------
__global__ __launch_bounds__(256) void zero_kernel(int* pcount, int* ccount) {
    if (threadIdx.x == 0 && blockIdx.x == 0) { *pcount = 0; *ccount = 0; }
}

// e_sq via numpy-pairwise replica (unchanged).
__global__ __launch_bounds__(256) void esq_np_kernel(const float* __restrict__ emb,
                                                     float* __restrict__ esq) {
    const int k = blockIdx.x * 256 + threadIdx.x;
    esq[k] = np_sumsq_256(emb + (size_t)k * C_);
}

// ---------------------------------------------------------------------------
// emb f32 -> hi/lo bf16 planes in STAGED-TILE layout (unchanged):
// chunk (kb*4+ct) is 16KB/plane: [cg8][128][8].
// ---------------------------------------------------------------------------
__global__ __launch_bounds__(256) void cvt_e_kernel(const float* __restrict__ emb,
                                                    u16* __restrict__ et_hi,
                                                    u16* __restrict__ et_lo) {
    const int tid = threadIdx.x;
    const int k  = (blockIdx.x << 5) + (tid & 31);
    const int cg = tid >> 5;
    const int kb = k >> 7;
    const int kr = k & 127;
#pragma unroll
    for (int ct = 0; ct < 4; ++ct) {
        const int c = (ct << 6) + (cg << 3);
        const float* src = emb + (size_t)k * C_ + c;
        u16 h[8], l[8];
#pragma unroll
        for (int i = 0; i < 8; ++i) {
            const float f = src[i];
            h[i] = bf16_rne(f);
            l[i] = bf16_rne(f - bf16_to_f(h[i]));
        }
        const size_t off = ((size_t)((kb << 2) + ct) << 13) + (cg << 10) + (kr << 3);
        *(uint4*)(et_hi + off) = pack8(h);
        *(uint4*)(et_lo + off) = pack8(l);
    }
}

// ---------------------------------------------------------------------------
// MFMA bf16x3 scoring + top-2 + flag. v7: r8 schedule (measured optimum) +
// FUSED x conversion — the cvt_x kernel and the 128MB xt round-trip are
// eliminated. Per ct-quarter the block (A) stages 16KB of raw f32 x into the
// E-region scratch with coalesced float4 lane reads, (B) converts 8 channels
// per thread with the IDENTICAL bf16_rne hi/lo math into the same
// [ct][cg][row64][8] X layout the k-loop reads. Scores bitwise identical.
// 512 threads (8 waves, 2x4), 64 px x 1024 codes; LDS 80KB; 2 blocks/CU.
// ---------------------------------------------------------------------------
__global__ __launch_bounds__(512, 4) void vq_main_mfma(const float* __restrict__ x,
                                                       const u16* __restrict__ et_hi,
                                                       const u16* __restrict__ et_lo,
                                                       const float* __restrict__ esq,
                                                       int* __restrict__ idx_arr,
                                                       float* __restrict__ m1_arr,
                                                       int* __restrict__ plist,
                                                       int* __restrict__ pcount) {
    __shared__ __align__(16) char smem[81920];
    // XH [ct4][cg8][row64][8] @0; XL @32768; E / raw-f32 scratch @65536 (16KB)
    float* r_m1 = (float*)(smem + 65536);   // aliases E after the k-loop
    float* r_m2 = (float*)(smem + 69888);
    int*   r_i1 = (int*)(smem + 74240);

    const int tid  = threadIdx.x;
    const int lane = tid & 63;
    const int wid  = tid >> 6;        // 0..7
    const int wr   = wid >> 2;        // 0..1 (pixel half)
    const int wc   = wid & 3;         // 0..3 (code quarter)
    const int l15 = lane & 15, l4 = lane >> 4;
    // bijective XCD swizzle: consecutive-on-XCD blocks share the E stream
    const int bid = blockIdx.x;
    const int swz = ((bid & 7) << 7) + (bid >> 3);
    const int p0 = swz * 64;
    const int b   = p0 >> 10;
    const int hw0 = p0 & 1023;

    // ---- fused cvt_x prologue: build XH/XL from f32 x (4 ct phases) ----
    for (int ct = 0; ct < 4; ++ct) {
        // (A) raw f32 stage: 64 channels x 64 px -> E scratch [cl][px]
#pragma unroll
        for (int r = 0; r < 2; ++r) {
            const int task = (r << 9) + tid;        // 0..1023
            const int cl = task >> 4, seg = task & 15;
            const float4 v = *(const float4*)(x + ((size_t)(b * C_ + (ct << 6) + cl)) * HW_ +
                                              hw0 + (seg << 2));
            *(float4*)(smem + 65536 + (cl << 8) + (seg << 4)) = v;
        }
        __syncthreads();
        // (B) convert 8 channels/thread, identical RNE hi/lo, b128 writes
        {
            const int cg = tid >> 6, px = tid & 63;
            u16 h[8], l[8];
#pragma unroll
            for (int i = 0; i < 8; ++i) {
                const float f = *(const float*)(smem + 65536 + (((cg << 3) + i) << 8) + (px << 2));
                h[i] = bf16_rne(f);
                l[i] = bf16_rne(f - bf16_to_f(h[i]));
            }
            *(uint4*)(smem + (ct << 13) + (cg << 10) + (px << 4)) = pack8(h);
            *(uint4*)(smem + 32768 + (ct << 13) + (cg << 10) + (px << 4)) = pack8(l);
        }
        __syncthreads();
    }

    float m1[2], m2[2]; int i1[2];
#pragma unroll
    for (int i = 0; i < 2; ++i) { m1[i] = 3.0e38f; m2[i] = 3.0e38f; i1[i] = 0; }

    for (int kt = 0; kt < 8; ++kt) {
        float4v acc[2][2];
        const float4v zero4 = {0.f, 0.f, 0.f, 0.f};
#pragma unroll
        for (int pf = 0; pf < 2; ++pf)
#pragma unroll
            for (int cf = 0; cf < 2; ++cf) acc[pf][cf] = zero4;

        for (int kg = 0; kg < 8; ++kg) {    // 32-channel steps, ascending
            __syncthreads();                // E free (prev step consumed / prologue done)
            {   // stage E: 8KB hi + 8KB lo, 2 loads/wave
                const size_t ch = (((size_t)((kt << 2) + (kg >> 1))) << 14) + ((size_t)(kg & 1) << 13);
                __builtin_amdgcn_global_load_lds(
                    (gvoid*)((const char*)et_hi + ch + (wid << 10) + (lane << 4)),
                    (lvoid*)(smem + 65536 + (wid << 10)), 16, 0, 0);
                __builtin_amdgcn_global_load_lds(
                    (gvoid*)((const char*)et_lo + ch + (wid << 10) + (lane << 4)),
                    (lvoid*)(smem + 65536 + 8192 + (wid << 10)), 16, 0, 0);
            }
            __syncthreads();                // E landed (vmcnt drained by all waves)

            bf16x8v eh[2], el[2];
#pragma unroll
            for (int cf = 0; cf < 2; ++cf) {
                const int eo = 65536 + (l4 << 11) + (((wc << 5) + (cf << 4) + l15) << 4);
                eh[cf] = *(const bf16x8v*)(smem + eo);
                el[cf] = *(const bf16x8v*)(smem + 8192 + eo);
            }
            const int ct = kg >> 1;
            const int cg = ((kg & 1) << 2) + l4;
#pragma unroll
            for (int pf = 0; pf < 2; ++pf) {
                const int xo = (ct << 13) + (cg << 10) + (((wr << 5) + (pf << 4) + l15) << 4);
                const bf16x8v xh = *(const bf16x8v*)(smem + xo);
                const bf16x8v xl = *(const bf16x8v*)(smem + 32768 + xo);
#pragma unroll
                for (int cf = 0; cf < 2; ++cf) {
                    acc[pf][cf] = __builtin_amdgcn_mfma_f32_16x16x32_bf16(eh[cf], xh, acc[pf][cf], 0, 0, 0);
                    acc[pf][cf] = __builtin_amdgcn_mfma_f32_16x16x32_bf16(eh[cf], xl, acc[pf][cf], 0, 0, 0);
                    acc[pf][cf] = __builtin_amdgcn_mfma_f32_16x16x32_bf16(el[cf], xh, acc[pf][cf], 0, 0, 0);
                }
            }
        }
        // top-2 update; k ascending per pixel slot (cf outer, reg inner)
        const int k0 = kt << 7;
#pragma unroll
        for (int cf = 0; cf < 2; ++cf) {
            const int kb = k0 + (wc << 5) + (cf << 4) + (l4 << 2);
            const float4v ev = *(const float4v*)(esq + kb);
#pragma unroll
            for (int pf = 0; pf < 2; ++pf) {
#pragma unroll
                for (int r = 0; r < 4; ++r) {
                    const float s = fmaf(-2.0f, acc[pf][cf][r], ev[r]);
                    const int k = kb + r;
                    if (s < m1[pf])      { m2[pf] = m1[pf]; m1[pf] = s; i1[pf] = k; }
                    else if (s < m2[pf]) { m2[pf] = s; }
                }
            }
        }
    }

    __syncthreads();    // all E reads done; alias reduction arrays
#pragma unroll
    for (int pf = 0; pf < 2; ++pf) {
        const int p = (wr << 5) + (pf << 4) + l15;   // 0..63
        const int slot = (wc << 2) + l4;             // 0..15
        r_m1[p * 17 + slot] = m1[pf]; r_m2[p * 17 + slot] = m2[pf]; r_i1[p * 17 + slot] = i1[pf];
    }
    __syncthreads();
    if (tid < 64) {
        const int p = tid;
        float M1 = r_m1[p * 17 + 0], M2 = r_m2[p * 17 + 0];
        int   I1 = r_i1[p * 17 + 0];
        for (int t = 1; t < 16; ++t) {
            const float a1 = r_m1[p * 17 + t], a2 = r_m2[p * 17 + t];
            const int   ai = r_i1[p * 17 + t];
            if (a1 < M1 || (a1 == M1 && ai < I1)) { M2 = fminf(M1, a2); M1 = a1; I1 = ai; }
            else                                  { M2 = fminf(M2, a1); }
        }
        const int pix = p0 + p;
        idx_arr[pix] = I1;
        m1_arr[pix] = M1;
        if (M2 - M1 <= TAU_FLAG) {
            int pos = atomicAdd(pcount, 1);
            if (pos < MAXFLAG) plist[pos] = pix;
        }
    }
}

// ---------------------------------------------------------------------------
// gather_x v2 (unchanged from round 13): 8 flagged slots per block; emits
// xg, xsq, best-init and the bf16 xgt tiles directly.
// ---------------------------------------------------------------------------
__global__ __launch_bounds__(256) void gather_x_kernel(const float* __restrict__ x,
                                                       const int* __restrict__ plist,
                                                       const int* __restrict__ pcount,
                                                       float* __restrict__ xg,
                                                       float* __restrict__ xsq_arr,
                                                       u64* __restrict__ best_arr,
                                                       u16* __restrict__ xgt_hi,
                                                       u16* __restrict__ xgt_lo) {
    __shared__ float xs[8][264];
    __shared__ float rsum[8][16];
    __shared__ int pix_s[8];
    const int nflag = min(*pcount, MAXFLAG);
    const int sbase = blockIdx.x << 3;
    if (sbase >= nflag) return;
    const int nact = min(8, nflag - sbase);
    const int tid = threadIdx.x;

    if (tid < 8) pix_s[tid] = (tid < nact) ? plist[sbase + tid] : plist[sbase];
    __syncthreads();
#pragma unroll
    for (int p = 0; p < 8; ++p) {       // 8 independent scattered loads in flight
        const int pix = pix_s[p];
        const int b = pix >> 10, hw = pix & 1023;
        const float v = x[((size_t)(b * C_ + tid)) * HW_ + hw];
        xs[p][tid] = v;
        if (p < nact) xg[(size_t)(sbase + p) * C_ + tid] = v;
    }
    __syncthreads();
    if (tid < 128) {                    // 8 slots x 16 chains, exact np tree
        const int p = tid >> 4, h = (tid >> 3) & 1, j = tid & 7;
        const float* q = &xs[p][h * 128];
        float r = fmul_x(q[j], q[j]);
        for (int i = 8; i < 128; i += 8) r = fadd_x(r, fmul_x(q[i + j], q[i + j]));
        rsum[p][h * 8 + j] = r;
    }
    __syncthreads();
    if (tid < 8 && tid < nact) {
        const float* r0 = &rsum[tid][0];
        const float h0 = fadd_x(fadd_x(fadd_x(r0[0], r0[1]), fadd_x(r0[2], r0[3])),
                                fadd_x(fadd_x(r0[4], r0[5]), fadd_x(r0[6], r0[7])));
        const float h1 = fadd_x(fadd_x(fadd_x(r0[8], r0[9]), fadd_x(r0[10], r0[11])),
                                fadd_x(fadd_x(r0[12], r0[13]), fadd_x(r0[14], r0[15])));
        xsq_arr[sbase + tid] = fadd_x(h0, h1);
        best_arr[sbase + tid] = ~0ull;
    }
    // emit bf16 staged tiles (identical values & layout to cvt_e pattern)
    {
        const int p  = tid >> 5;            // 0..7
        const int ct = (tid >> 3) & 3;      // 0..3
        const int cg = tid & 7;             // 0..7
        if (p < nact) {
            const int s  = sbase + p;
            const int sb = s >> 7;
            const int sr = s & 127;
            const int c = (ct << 6) + (cg << 3);
            u16 h[8], l[8];
#pragma unroll
            for (int i = 0; i < 8; ++i) {
                const float f = xs[p][c + i];
                h[i] = bf16_rne(f);
                l[i] = bf16_rne(f - bf16_to_f(h[i]));
            }
            const size_t off = ((size_t)((sb << 2) + ct) << 13) + (cg << 10) + (sr << 3);
            *(uint4*)(xgt_hi + off) = pack8(h);
            *(uint4*)(xgt_lo + off) = pack8(l);
        }
    }
}

// ---------------------------------------------------------------------------
// MFMA scan of flagged slots (unchanged): 128 slots x 128 codes per block;
// candidates appended to a global list.
// ---------------------------------------------------------------------------
__global__ __launch_bounds__(256) void vq_scan_mfma(const u16* __restrict__ xgt_hi,
                                                    const u16* __restrict__ xgt_lo,
                                                    const u16* __restrict__ et_hi,
                                                    const u16* __restrict__ et_lo,
                                                    const float* __restrict__ esq,
                                                    const float* __restrict__ m1_arr,
                                                    const int* __restrict__ plist,
                                                    const int* __restrict__ pcount,
                                                    u32* __restrict__ cand,
                                                    int* __restrict__ ccount) {
    __shared__ __align__(16) u16 xsb_hi[8192], xsb_lo[8192], esb_hi[8192], esb_lo[8192];
    __shared__ float thresh_s[128];

    const int nflag = min(*pcount, MAXFLAG);
    const int st = blockIdx.x >> 3;     // slot tile
    const int kt = blockIdx.x & 7;      // code tile
    const int p0 = st << 7;
    if (p0 >= nflag) return;
    const int tid = threadIdx.x;
    if (tid < 128) {
        const int s = p0 + tid;
        thresh_s[tid] = (s < nflag) ? (m1_arr[plist[s]] + CAND_MARGIN) : -3.0e38f;
    }

    const int lane = tid & 63;
    const int wid  = tid >> 6;
    const int wr = wid >> 1, wc = wid & 1;
    const int l15 = lane & 15, l4 = lane >> 4;

    const char* xhb = (const char*)xgt_hi + ((size_t)st << 16);
    const char* xlb = (const char*)xgt_lo + ((size_t)st << 16);
    const char* ehb = (const char*)et_hi + ((size_t)(kt << 2) << 14);
    const char* elb = (const char*)et_lo + ((size_t)(kt << 2) << 14);

    float4v acc[4][4];
    const float4v zero4 = {0.f, 0.f, 0.f, 0.f};
#pragma unroll
    for (int pf = 0; pf < 4; ++pf)
#pragma unroll
        for (int cf = 0; cf < 4; ++cf) acc[pf][cf] = zero4;

    for (int ct = 0; ct < 4; ++ct) {
        const int coff = ct << 14;
        __syncthreads();
#pragma unroll
        for (int i = 0; i < 4; ++i) {
            const int off = (((i << 2) + wid) << 10);
            const int src = off + (lane << 4);
            __builtin_amdgcn_global_load_lds((gvoid*)(xhb + coff + src),
                (lvoid*)((char*)xsb_hi + off), 16, 0, 0);
            __builtin_amdgcn_global_load_lds((gvoid*)(xlb + coff + src),
                (lvoid*)((char*)xsb_lo + off), 16, 0, 0);
            __builtin_amdgcn_global_load_lds((gvoid*)(ehb + coff + src),
                (lvoid*)((char*)esb_hi + off), 16, 0, 0);
            __builtin_amdgcn_global_load_lds((gvoid*)(elb + coff + src),
                (lvoid*)((char*)esb_lo + off), 16, 0, 0);
        }
        __syncthreads();
#pragma unroll
        for (int ks = 0; ks < 2; ++ks) {
            const int cgb = (ks << 2) + l4;
            const int ebase = (cgb << 7) + (wc << 6) + l15;
            const int xbase = (cgb << 7) + (wr << 6) + l15;
            bf16x8v eh[4], el[4];
#pragma unroll
            for (int cf = 0; cf < 4; ++cf) {
                const int eo = (ebase + (cf << 4)) << 3;
                eh[cf] = *(const bf16x8v*)(esb_hi + eo);
                el[cf] = *(const bf16x8v*)(esb_lo + eo);
            }
#pragma unroll
            for (int pf = 0; pf < 4; ++pf) {
                const int xo = (xbase + (pf << 4)) << 3;
                const bf16x8v xh = *(const bf16x8v*)(xsb_hi + xo);
                const bf16x8v xl = *(const bf16x8v*)(xsb_lo + xo);
#pragma unroll
                for (int cf = 0; cf < 4; ++cf) {
                    acc[pf][cf] = __builtin_amdgcn_mfma_f32_16x16x32_bf16(eh[cf], xh, acc[pf][cf], 0, 0, 0);
                    acc[pf][cf] = __builtin_amdgcn_mfma_f32_16x16x32_bf16(eh[cf], xl, acc[pf][cf], 0, 0, 0);
                    acc[pf][cf] = __builtin_amdgcn_mfma_f32_16x16x32_bf16(el[cf], xh, acc[pf][cf], 0, 0, 0);
                }
            }
        }
    }

    const int k0 = kt << 7;
#pragma unroll
    for (int cf = 0; cf < 4; ++cf) {
        const int kb = k0 + (wc << 6) + (cf << 4) + (l4 << 2);
        const float4v ev = *(const float4v*)(esq + kb);
#pragma unroll
        for (int pf = 0; pf < 4; ++pf) {
            const int slotl = (wr << 6) + (pf << 4) + l15;
            const int slotg = p0 + slotl;
            if (slotg < nflag) {
                const float th = thresh_s[slotl];
#pragma unroll
                for (int r = 0; r < 4; ++r) {
                    const float s = fmaf(-2.0f, acc[pf][cf][r], ev[r]);
                    if (s <= th) {
                        int pos = atomicAdd(ccount, 1);
                        if (pos < MAXCAND) cand[pos] = ((u32)slotg << 10) | (u32)(kb + r);
                    }
                }
            }
        }
    }
}

// ---------------------------------------------------------------------------
// Exact np rescore: one thread per candidate (unchanged).
// ---------------------------------------------------------------------------
__global__ __launch_bounds__(256) void vq_cand_np(const float* __restrict__ xg,
                                                  const float* __restrict__ emb,
                                                  const float* __restrict__ esq,
                                                  const float* __restrict__ xsq_arr,
                                                  const u32* __restrict__ cand,
                                                  const int* __restrict__ ccount,
                                                  u64* __restrict__ best_arr) {
    const int ncand = min(*ccount, MAXCAND);
    const int id = blockIdx.x * 256 + threadIdx.x;
    if (id >= ncand) return;
    const u32 v = cand[id];
    const int slot = (int)(v >> 10);
    const int k = (int)(v & 1023u);
    const float cr = np_einsum_dot_256(xg + (size_t)slot * C_, emb + (size_t)k * C_);
    const float d2 = fadd_x(fsub_x(xsq_arr[slot], fmul_x(2.0f, cr)), esq[k]);
    const u64 pk = ((u64)__float_as_uint(d2) << 32) | (unsigned)k;
    atomicMin(&best_arr[slot], pk);
}

__global__ __launch_bounds__(256) void finalize_kernel(const u64* __restrict__ best_arr,
                                                       const int* __restrict__ plist,
                                                       const int* __restrict__ pcount,
                                                       int* __restrict__ idx_arr) {
    const int nflag = min(*pcount, MAXFLAG);
    const int s = blockIdx.x * 256 + threadIdx.x;
    if (s >= nflag) return;
    idx_arr[plist[s]] = (int)(best_arr[s] & 0xffffffffu);
}

// ---------------------------------------------------------------------------
// gather + STE: out = fl(fl(q - x) + x). Runs LAST. (unchanged)
// ---------------------------------------------------------------------------
__global__ __launch_bounds__(256) void gather_kernel(const float* __restrict__ x,
                                                     const float* __restrict__ emb,
                                                     const int* __restrict__ idx_arr,
                                                     float* __restrict__ out) {
    __shared__ int idx_s[128];
    __shared__ float qs[32][257];
    const int tid = threadIdx.x;
    const int blk = blockIdx.x;
    const int b   = blk >> 3;
    const int hw0 = (blk & 7) << 7;
    if (tid < 128) idx_s[tid] = idx_arr[blk * 128 + tid];
    __syncthreads();
    const int cidx = tid >> 5;          // 0..7
    const int px   = tid & 31;          // 0..31
    for (int ch = 0; ch < 4; ++ch) {
        const int p0c = ch << 5;
#pragma unroll 8
        for (int r = 0; r < 32; ++r)
            qs[r][tid] = emb[(size_t)idx_s[p0c + r] * C_ + tid];
        __syncthreads();
#pragma unroll
        for (int j = 0; j < 32; ++j) {
            const int c = (j << 3) + cidx;
            const size_t o = ((size_t)b * C_ + c) * HW_ + hw0 + p0c + px;
            const float q  = qs[px][c];
            const float xv = x[o];
            out[o] = fadd_x(fsub_x(q, xv), xv);
        }
        __syncthreads();
    }
}

extern "C" void kernel_launch(void* const* d_in, const int* in_sizes, int n_in,
                              void* d_out, int out_size, void* d_ws, size_t ws_size,
                              hipStream_t stream) {
    const float* x   = (const float*)d_in[0];
    const float* emb = (const float*)d_in[1];
    float* out = (float*)d_out;
    char* ws = (char*)d_ws;

    float* esq     = (float*)ws;                 // 4 KB
    int*   pcount  = (int*)(ws + 4096);
    int*   ccount  = (int*)(ws + 8192);
    int*   plist   = (int*)(ws + 12288);         // 32 KB
    float* m1_arr  = (float*)(ws + 65536);       // 256 KB
    int*   idx_arr = (int*)(ws + 327680);        // 256 KB
    float* xsq_arr = (float*)(ws + 589824);      // 32 KB
    u64*   best_arr= (u64*)(ws + 622592);        // 64 KB
    u32*   cand    = (u32*)(ws + 688128);        // 256 KB
    u16*   et_hi   = (u16*)(ws + 983040);        // 512 KB (tiled layout)
    u16*   et_lo   = (u16*)(ws + 1507328);       // 512 KB (total ws ~2 MB)

    // The out buffer hosts the rescue scratch (xg + xgt) until gather runs.
    float* xg      = (float*)d_out;                           // 8 MB
    u16*   xgt_hi  = (u16*)((char*)d_out + (8u << 20));       // 4 MB
    u16*   xgt_lo  = (u16*)((char*)d_out + (12u << 20));      // 4 MB

    zero_kernel<<<1, 256, 0, stream>>>(pcount, ccount);
    esq_np_kernel<<<K_ / 256, 256, 0, stream>>>(emb, esq);
    cvt_e_kernel<<<K_ / 32, 256, 0, stream>>>(emb, et_hi, et_lo);
    vq_main_mfma<<<NPIX / 64, 512, 0, stream>>>(x, et_hi, et_lo, esq,
                                                idx_arr, m1_arr, plist, pcount);
    gather_x_kernel<<<MAXFLAG / 8, 256, 0, stream>>>(x, plist, pcount, xg, xsq_arr,
                                                     best_arr, xgt_hi, xgt_lo);
    vq_scan_mfma<<<(MAXFLAG / 128) * 8, 256, 0, stream>>>(xgt_hi, xgt_lo, et_hi, et_lo,
                                                          esq, m1_arr, plist, pcount,
                                                          cand, ccount);
    vq_cand_np<<<MAXCAND / 256, 256, 0, stream>>>(xg, emb, esq, xsq_arr, cand, ccount,
                                                  best_arr);
    finalize_kernel<<<MAXFLAG / 256, 256, 0, stream>>>(best_arr, plist, pcount, idx_arr);
    gather_kernel<<<NPIX / 128, 256, 0, stream>>>(x, emb, idx_arr, out);
}